// Round 16
// baseline (800.107 us; speedup 1.0000x reference)
//
#include <hip/hip_runtime.h>

#define NSAMP 32768
#define INB   4
#define HIDN  4
#define CHN   2
#define OUTD  10
#define NPIX  196
#define NMID  194
#define BLK   512
#define NBLK  (NSAMP / BLK)            /* 64 blocks == wave width, 1 sample/thread */
#define INV_ROWS 1.52587890625e-05f    /* 1 / (N*CH) = 1/65536 */
#define BN_EPS 1e-5f
#define SENT  0xFFFFFFFFFFFFFFFFull    /* NaN-pair sentinel, unreachable by finite math */
/* ws: slots[NMID][NBLK][4] u64 — fused store/poll barrier (R8): wave 0 only,
   lane l polls block l's 32B slot, detection == data delivery. R14 added the
   M-precompute poll-shadow. R15: SELF-QUENCHING poll — a lane stops issuing
   loads once its slot is valid, so steady-state poll traffic on the 16 slot
   cache lines collapses to the laggards (tests the LLC-congestion theory). */
#define WS_BYTES ((size_t)NMID * NBLK * 4 * sizeof(unsigned long long))

__device__ __forceinline__ float xcomp(const float4& v, int j) {
    return j == 0 ? v.x : j == 1 ? v.y : j == 2 ? v.z : v.w;
}

__global__ __launch_bounds__(BLK, 1)
void ttbn_main(const float* __restrict__ x,  const float* __restrict__ wf,
               const float* __restrict__ wm, const float* __restrict__ wl,
               const float* __restrict__ gamma, const float* __restrict__ beta,
               float* __restrict__ out, unsigned long long* __restrict__ slots)
{
    __shared__ float pb[BLK / 64][8];
    __shared__ float totl[8];
    const int tid = threadIdx.x;
    const int ln  = tid & 63, wv = tid >> 6;
    const long n  = (long)blockIdx.x * BLK + tid;

    float gm[HIDN], bt[HIDN];
#pragma unroll
    for (int h = 0; h < HIDN; ++h) { gm[h] = gamma[h]; bt[h] = beta[h]; }

    const float* xrow = x + n * (INB * NPIX);

    float4 xq[INB];               // current 4-pixel group per bond
#pragma unroll
    for (int i = 0; i < INB; ++i)
        xq[i] = *reinterpret_cast<const float4*>(xrow + i * NPIX);   // pixels 0-3

    // ---- y init from pixel 0 (no BN) ----
    float y[CHN][HIDN];
#pragma unroll
    for (int c = 0; c < CHN; ++c)
#pragma unroll
        for (int h = 0; h < HIDN; ++h) {
            float acc = 0.f;
#pragma unroll
            for (int i = 0; i < INB; ++i)
                acc = fmaf(xq[i].x, wf[i * (HIDN * CHN) + h * CHN + c], acc);
            y[c][h] = acc;
        }
    // ---- M_0 from pixel 1 ----
    float M[CHN][HIDN][HIDN];
#pragma unroll
    for (int c = 0; c < CHN; ++c)
#pragma unroll
        for (int r = 0; r < HIDN; ++r)
#pragma unroll
            for (int h = 0; h < HIDN; ++h) {
                float m = 0.f;
#pragma unroll
                for (int i = 0; i < INB; ++i)
                    m = fmaf(xq[i].y, wm[(r * 16 + i * 4 + h) * 2 + c], m);
                M[c][r][h] = m;
            }

    float yn[CHN][HIDN];

#pragma unroll 1
    for (int t = 0; t < NMID; ++t) {
        // ---- critical chain: yn = y·M (32 FMA) ----
#pragma unroll
        for (int c = 0; c < CHN; ++c)
#pragma unroll
            for (int h = 0; h < HIDN; ++h) {
                float acc = 0.f;
#pragma unroll
                for (int r = 0; r < HIDN; ++r)
                    acc = fmaf(y[c][r], M[c][r][h], acc);
                yn[c][h] = acc;
            }
        // ---- stats partials + wave reduce ----
        float red[8];
#pragma unroll
        for (int h = 0; h < HIDN; ++h) {
            red[h]     = yn[0][h] + yn[1][h];
            red[4 + h] = yn[0][h] * yn[0][h] + yn[1][h] * yn[1][h];
        }
#pragma unroll
        for (int j = 0; j < 8; ++j)
#pragma unroll
            for (int off = 32; off > 0; off >>= 1)
                red[j] += __shfl_down(red[j], off);
        if (ln == 0) {
#pragma unroll
            for (int j = 0; j < 8; ++j) pb[wv][j] = red[j];
        }
        __syncthreads();
        // ---- wave0 lanes 0-3: combine 8 waves, issue block-partial store ----
        if (wv == 0 && ln < 4) {
            float lo = 0.f, hi = 0.f;
#pragma unroll
            for (int w = 0; w < 8; ++w) {
                lo += pb[w][2 * ln];
                hi += pb[w][2 * ln + 1];
            }
            unsigned long long v = ((unsigned long long)__float_as_uint(hi) << 32)
                                 |  (unsigned long long)__float_as_uint(lo);
            __hip_atomic_store(&slots[((size_t)t * NBLK + blockIdx.x) * 4 + ln], v,
                               __ATOMIC_RELAXED, __HIP_MEMORY_SCOPE_AGENT);
        }
        // ---- poll shadow: next-step M (and x group) — independent of stats.
        //      Waves 1-7: runs while wave0 polls. Wave0: fits under commit. ----
        if (t < NMID - 1) {
            const int q = t + 2;            // pixel feeding M_{t+1}
            if ((q & 3) == 0) {
#pragma unroll
                for (int i = 0; i < INB; ++i)
                    xq[i] = *reinterpret_cast<const float4*>(xrow + i * NPIX + q);
            }
            float xv[INB];
#pragma unroll
            for (int i = 0; i < INB; ++i) xv[i] = xcomp(xq[i], q & 3);
            const float* w1 = wm + (size_t)(t + 1) * 128;
#pragma unroll
            for (int c = 0; c < CHN; ++c)
#pragma unroll
                for (int r = 0; r < HIDN; ++r)
#pragma unroll
                    for (int h = 0; h < HIDN; ++h) {
                        float m = 0.f;
#pragma unroll
                        for (int i = 0; i < INB; ++i)
                            m = fmaf(xv[i], w1[(r * 16 + i * 4 + h) * 2 + c], m);
                        M[c][r][h] = m;
                    }
        }
        // ---- wave0: self-quenching sentinel poll over all 64 block-slots ----
        if (wv == 0) {
            const unsigned long long* ps = &slots[((size_t)t * NBLK + ln) * 4];
            unsigned long long q0 = SENT, q1 = SENT, q2 = SENT, q3 = SENT;
            bool done = false;
            while (true) {
                if (!done) {   // exec-masked: finished lanes issue NO loads
                    q0 = __hip_atomic_load(&ps[0], __ATOMIC_RELAXED, __HIP_MEMORY_SCOPE_AGENT);
                    q1 = __hip_atomic_load(&ps[1], __ATOMIC_RELAXED, __HIP_MEMORY_SCOPE_AGENT);
                    q2 = __hip_atomic_load(&ps[2], __ATOMIC_RELAXED, __HIP_MEMORY_SCOPE_AGENT);
                    q3 = __hip_atomic_load(&ps[3], __ATOMIC_RELAXED, __HIP_MEMORY_SCOPE_AGENT);
                    done = (q0 != SENT) && (q1 != SENT) && (q2 != SENT) && (q3 != SENT);
                }
                if (__all(done)) break;
                __builtin_amdgcn_s_sleep(1);
            }
            float sm[8];
            sm[0] = __uint_as_float((unsigned)q0); sm[1] = __uint_as_float((unsigned)(q0 >> 32));
            sm[2] = __uint_as_float((unsigned)q1); sm[3] = __uint_as_float((unsigned)(q1 >> 32));
            sm[4] = __uint_as_float((unsigned)q2); sm[5] = __uint_as_float((unsigned)(q2 >> 32));
            sm[6] = __uint_as_float((unsigned)q3); sm[7] = __uint_as_float((unsigned)(q3 >> 32));
#pragma unroll
            for (int j = 0; j < 8; ++j)
#pragma unroll
                for (int off = 1; off < 64; off <<= 1)
                    sm[j] += __shfl_xor(sm[j], off);
            if (ln < 8) totl[ln] = sm[ln];
        }
        __syncthreads();
        // ---- BN apply ----
        float smv[8];
#pragma unroll
        for (int j = 0; j < 8; ++j) smv[j] = totl[j];
#pragma unroll
        for (int h = 0; h < HIDN; ++h) {
            float m  = smv[h] * INV_ROWS;
            float v  = fmaf(-m, m, smv[4 + h] * INV_ROWS);
            float is = rsqrtf(v + BN_EPS) * gm[h];
            float sh = bt[h] - m * is;
            y[0][h] = fmaf(yn[0][h], is, sh);
            y[1][h] = fmaf(yn[1][h], is, sh);
        }
    }

    // ---- final step: pixel 195 (= xq comp 3, group 48) with wl, no BN ----
    {
        float xv[INB];
#pragma unroll
        for (int i = 0; i < INB; ++i) xv[i] = xq[i].w;
        float o0[OUTD], o1[OUTD];
#pragma unroll
        for (int od = 0; od < OUTD; ++od) { o0[od] = 0.f; o1[od] = 0.f; }
#pragma unroll
        for (int r = 0; r < HIDN; ++r)
#pragma unroll
            for (int i = 0; i < INB; ++i) {
                float p0 = y[0][r] * xv[i];
                float p1 = y[1][r] * xv[i];
                const float* wri = wl + r * (INB * OUTD * CHN) + i * (OUTD * CHN);
#pragma unroll
                for (int od = 0; od < OUTD; ++od) {
                    o0[od] = fmaf(p0, wri[od * CHN + 0], o0[od]);
                    o1[od] = fmaf(p1, wri[od * CHN + 1], o1[od]);
                }
            }
        float tmp[20];
#pragma unroll
        for (int od = 0; od < OUTD; ++od) { tmp[od] = o0[od]; tmp[10 + od] = o1[od]; }
        float4* o4 = reinterpret_cast<float4*>(out + n * (CHN * OUTD));
#pragma unroll
        for (int q = 0; q < 5; ++q)
            o4[q] = make_float4(tmp[q * 4], tmp[q * 4 + 1], tmp[q * 4 + 2], tmp[q * 4 + 3]);
    }
}

extern "C" void kernel_launch(void* const* d_in, const int* in_sizes, int n_in,
                              void* d_out, int out_size, void* d_ws, size_t ws_size,
                              hipStream_t stream) {
    const float* x     = (const float*)d_in[0];
    const float* wf    = (const float*)d_in[1];
    const float* wm    = (const float*)d_in[2];
    const float* wl    = (const float*)d_in[3];
    const float* gamma = (const float*)d_in[4];
    const float* beta  = (const float*)d_in[5];
    float*       out   = (float*)d_out;
    unsigned long long* slots = (unsigned long long*)d_ws;

    // sentinel-fill the slot array (0xFF bytes == SENT); stream-ordered before kernel
    hipMemsetAsync(d_ws, 0xFF, WS_BYTES, stream);

    void* args[] = { &x, &wf, &wm, &wl, &gamma, &beta, &out, &slots };
    hipLaunchCooperativeKernel((void*)ttbn_main, dim3(NBLK), dim3(BLK),
                               args, 0, stream);
}